// Round 5
// baseline (3872.084 us; speedup 1.0000x reference)
//
#include <hip/hip_runtime.h>
#include <cstdint>
#include <cstddef>

// Problem constants
#define TT 1024
#define NB 64
#define HD 256
#define NG 768   // 3*H

typedef short bhalf8 __attribute__((ext_vector_type(8)));   // 8 bf16 (4 VGPRs)
typedef float f32x4  __attribute__((ext_vector_type(4)));   // MFMA accumulator

#define LOG2E  1.4426950408889634f
#define LOG2E2 2.8853900817779268f   // 2*log2e (c-gate rows: folds the 2x in tanh)

__device__ __forceinline__ float bf2f(unsigned short s) {
  return __uint_as_float(((unsigned)s) << 16);
}
__device__ __forceinline__ unsigned cvt_pk_bf16(float lo, float hi) {
  unsigned r;
  asm("v_cvt_pk_bf16_f32 %0, %1, %2" : "=v"(r) : "v"(lo), "v"(hi));
  return r;
}
// single-instruction clamp to +-24 (v_med3_f32)
__device__ __forceinline__ float clamp24(float x) {
  return __builtin_amdgcn_fmed3f(x, -24.0f, 24.0f);
}
// Batched reciprocal: 4 divides for the price of 1 v_rcp + 9 v_mul.
// All inputs in [1, 1+2^24] -> product <= 2^97, no overflow.
__device__ __forceinline__ void inv4(float d0, float d1, float d2, float d3,
                                     float& i0, float& i1, float& i2, float& i3) {
  float p2 = d0 * d1;
  float p3 = p2 * d2;
  float p4 = p3 * d3;
  float r  = __builtin_amdgcn_rcpf(p4);
  i3 = r * p3;
  float r3 = r * d3;      // 1/p3
  i2 = r3 * p2;
  float r2 = r3 * d2;     // 1/p2
  i1 = r2 * d0;
  i0 = r2 * d1;
}

// gx layout: [dir][slice(4)][t][g][b16]  (slice = batch/16, b16 = batch%16)
// gx values are PRESCALED: i/o-gate rows by log2e, c-gate rows by 2*log2e.
#define GX_SLICE ((size_t)TT * NG * 16)

// ---- cross-block h exchange state (module globals: no ws-size assumptions,
//      zero runtime allocation; flags re-zeroed by gx_kernel every launch) ----
__device__ uint2    hxch[2][16][512];   // [step parity][block][thread] packed bf16 h
__device__ unsigned rec_flags[16];      // monotonic step counters

// ---------------------------------------------------------------------------
// Kernel 1: gx = (X @ W_ih^T + biases) * gate_scale, bf16, swizzled layout.
// 1D grid 768 with XCD-aware swizzle: the 12 gate-tile blocks that share one
// X t-tile all land on the same XCD -> X re-reads (12x64MB) served from that
// XCD's L2 instead of L3/HBM; W_ih becomes L2-resident per XCD.
// ---------------------------------------------------------------------------
__attribute__((amdgpu_flat_work_group_size(1024, 1024)))
__attribute__((amdgpu_waves_per_eu(4, 4)))
__global__ void gx_kernel(const float* __restrict__ X,
                          const float* __restrict__ wih_f, const float* __restrict__ bih_f,
                          const float* __restrict__ bhh_f,
                          const float* __restrict__ wih_b, const float* __restrict__ bih_b,
                          const float* __restrict__ bhh_b,
                          unsigned short* __restrict__ gx) {
  const int tid = threadIdx.x;
  // XCD swizzle: xcd = bid&7; within XCD: 12 gate-tiles x 8 t-tiles
  const int bid  = blockIdx.x;
  const int xcd  = bid & 7;
  const int i    = bid >> 3;           // 0..95
  const int n0   = (i % 12) * 64;      // gate-col tile (single gate type)
  const int t0   = (xcd + 8 * (i / 12)) * 16;

  if (bid == 0 && tid < 16) rec_flags[tid] = 0;   // reset exchange flags (pre-rec)

  __shared__ unsigned short Al[2][64][264];   // X tile [buf][b][k], double-buffered

  const int lane = tid & 63, w = tid >> 6, quad = lane >> 4, l15 = lane & 15;
  const int sl = w & 3;          // batch slice
  const int jt = w >> 2;         // gate subtile
  const int g  = n0 + jt * 16 + l15;   // this lane's gate row
  const float wsc = (n0 >= 256 && n0 < 512) ? LOG2E2 : LOG2E;

  // ---- W_ih fragments for both dirs, in registers (8 bhalf8 per dir) ----
  bhalf8 wreg[2][8];
#pragma unroll
  for (int dir = 0; dir < 2; ++dir) {
    const float* wih = dir ? wih_b : wih_f;
#pragma unroll
    for (int kt = 0; kt < 8; ++kt) {
      const float* wp = wih + (size_t)g * HD + kt * 32 + quad * 8;
      float4 v0 = *(const float4*)wp;
      float4 v1 = *(const float4*)(wp + 4);
      union { bhalf8 v; uint4 u; } pk;
      pk.u.x = cvt_pk_bf16(v0.x * wsc, v0.y * wsc);
      pk.u.y = cvt_pk_bf16(v0.z * wsc, v0.w * wsc);
      pk.u.z = cvt_pk_bf16(v1.x * wsc, v1.y * wsc);
      pk.u.w = cvt_pk_bf16(v1.z * wsc, v1.w * wsc);
      wreg[dir][kt] = pk.v;
    }
  }
  const float bias_f = (bih_f[g] + bhh_f[g]) * wsc;
  const float bias_b = (bih_b[g] + bhh_b[g]) * wsc;

#define STAGE_X(ttv, buf)                                                     \
  {                                                                           \
    const int t = t0 + (ttv);                                                 \
    _Pragma("unroll")                                                         \
    for (int ii = 0; ii < 4; ++ii) {                                          \
      int f4  = tid + ii * 1024;                                              \
      int row = f4 >> 6;                                                      \
      int kk  = (f4 & 63) * 4;                                                \
      float4 xv = *(const float4*)(X + ((size_t)row * TT + t) * HD + kk);     \
      uint2 p;                                                                \
      p.x = cvt_pk_bf16(xv.x, xv.y);                                          \
      p.y = cvt_pk_bf16(xv.z, xv.w);                                          \
      *(uint2*)&Al[buf][row][kk] = p;                                         \
    }                                                                         \
  }

  STAGE_X(0, 0);

  for (int tt = 0; tt < 16; ++tt) {
    const int buf = tt & 1;
    __syncthreads();              // Al[buf] staged & visible; prior reads done
    if (tt < 15) STAGE_X(tt + 1, buf ^ 1);

    f32x4 acc0 = {0.f, 0.f, 0.f, 0.f};   // dir 0
    f32x4 acc1 = {0.f, 0.f, 0.f, 0.f};   // dir 1
#pragma unroll
    for (int kt = 0; kt < 8; ++kt) {
      bhalf8 a = *(const bhalf8*)&Al[buf][16 * sl + l15][kt * 32 + quad * 8];
      acc0 = __builtin_amdgcn_mfma_f32_16x16x32_bf16(a, wreg[0][kt], acc0, 0, 0, 0);
      acc1 = __builtin_amdgcn_mfma_f32_16x16x32_bf16(a, wreg[1][kt], acc1, 0, 0, 0);
    }

    const int t = t0 + tt;
    {
      unsigned short* gs = gx + sl * GX_SLICE + (size_t)t * NG * 16 + g * 16 + quad * 4;
      uint2 p;
      p.x = cvt_pk_bf16(acc0[0] + bias_f, acc0[1] + bias_f);
      p.y = cvt_pk_bf16(acc0[2] + bias_f, acc0[3] + bias_f);
      *(uint2*)gs = p;
      unsigned short* gs1 = gs + 4 * GX_SLICE;
      uint2 q;
      q.x = cvt_pk_bf16(acc1[0] + bias_b, acc1[1] + bias_b);
      q.y = cvt_pk_bf16(acc1[2] + bias_b, acc1[3] + bias_b);
      *(uint2*)gs1 = q;
    }
  }
#undef STAGE_X
}

// ---------------------------------------------------------------------------
// Kernel 2: recurrence, H-SPLIT. 16 blocks = 2 dirs x 4 slices x 2 H-halves;
// 512 threads = 8 waves (2/SIMD, 256-reg budget). Each wave owns one 16-col
// gate triple (i,c,o) of its half -> 3 MFMA tiles, 4 h/thread. Per-CU MFMA
// halves vs the 8-block version. The partner half of h arrives each step via
// a double-buffered __device__ exchange (release/acquire, agent scope);
// partners (bid, bid^8) share an XCD under the empirical bid%8 mapping.
// Protocol: publish h_{s+1} -> flag=s+1; spin partner flag>=s+1; skew<=1 step
// and 2 buffers => slot can't be overwritten before consumption.
// ---------------------------------------------------------------------------
__attribute__((amdgpu_flat_work_group_size(512, 512)))
__attribute__((amdgpu_waves_per_eu(2, 2)))
__global__ void rec_kernel(const float* __restrict__ whh_f,
                           const float* __restrict__ whh_b,
                           const unsigned short* __restrict__ gx,
                           float* __restrict__ out) {
  const int tid  = threadIdx.x;
  const int lane = tid & 63, w = tid >> 6, quad = lane >> 4, l15 = lane & 15;
  const int bid  = blockIdx.x;         // 0..15
  const int half = bid >> 3;           // H-half
  const int r3   = bid & 7;
  const int dir  = r3 >> 2;
  const int b0   = (r3 & 3) * 16;
  const int pbid = bid ^ 8;            // partner block
  const float* whh = dir ? whh_b : whh_f;
  const unsigned short* gxd = gx + (size_t)dir * 4 * GX_SLICE + (size_t)(r3 & 3) * GX_SLICE;
  float* hn = out + (size_t)TT * NB * 512;
  float* cn = hn + (size_t)NB * 512;

  __shared__ uint4 wlds[8][8][64];   // 64 KB: [wave][kt][lane] W-frags, tile p=2
  __shared__ uint4 hk[2][8][64];     // 16 KB: [buf][kt][chunk] h fragment layout
  // chunk = quadA*16 + m : holds A[m][kt*32+quadA*8 .. +8) as 8 bf16

  // ---- load W_hh fragments (one-time), prescaled by gate type ----
  // wave w owns h-cols [half*128+16w, +16): gate row n = p*256 + half*128 + 16w + l15
  bhalf8 wreg[2][8];
#pragma unroll
  for (int p = 0; p < 3; ++p) {
    int n = p * 256 + half * 128 + 16 * w + l15;
    const float wscp = (p == 1) ? LOG2E2 : LOG2E;
#pragma unroll
    for (int kt = 0; kt < 8; ++kt) {
      const float* wp = whh + (size_t)n * HD + kt * 32 + quad * 8;
      float4 v0 = *(const float4*)wp;
      float4 v1 = *(const float4*)(wp + 4);
      union { bhalf8 v; uint4 u; } pk;
      pk.u.x = cvt_pk_bf16(v0.x * wscp, v0.y * wscp);
      pk.u.y = cvt_pk_bf16(v0.z * wscp, v0.w * wscp);
      pk.u.z = cvt_pk_bf16(v1.x * wscp, v1.y * wscp);
      pk.u.w = cvt_pk_bf16(v1.z * wscp, v1.w * wscp);
      if (p < 2) wreg[p][kt] = pk.v;
      else       wlds[w][kt][lane] = pk.u;
    }
  }

  // zero h_0 buffer (both halves; only hk[0] read at s=0)
  {
    uint4 z; z.x = z.y = z.z = z.w = 0;
    ((uint4*)hk[0])[tid] = z;
  }

  float cstate[4];
#pragma unroll
  for (int r = 0; r < 4; ++r) cstate[r] = 0.0f;

  int goff[3];
#pragma unroll
  for (int p = 0; p < 3; ++p) {
    int g = p * 256 + half * 128 + 16 * w + l15;
    goff[p] = g * 16 + quad * 4;     // within-slice offset (b16 = quad*4..+3)
  }

  // own / partner hk write bases: kt-block = half*4 + (w>>1)
  const int ktb_own  = half * 4 + (w >> 1);
  const int ktb_par  = (1 - half) * 4 + (w >> 1);
  const int chunk_base = (((w & 1) * 2 + (l15 >> 3)) * 16 + quad * 4) * 8 + (l15 & 7);

  __syncthreads();

  // uniform gx walk pointer: t=0 forward, t=TT-1 backward. One-past-range
  // prefetch on the last step stays inside the 192 MiB gx buffer.
  const unsigned short* gptr = gxd + (size_t)(dir ? (TT - 1) : 0) * NG * 16;
  const ptrdiff_t gstep = dir ? -(ptrdiff_t)((size_t)NG * 16) : (ptrdiff_t)((size_t)NG * 16);

  // output row pointer walk; h-col = half*128 + 16w + l15
  float* orow = out + ((size_t)(dir ? (TT - 1) : 0) * NB + b0 + quad * 4) * 512
                + dir * 256 + half * 128 + 16 * w + l15;
  const ptrdiff_t ostep = dir ? -(ptrdiff_t)(NB * 512) : (ptrdiff_t)(NB * 512);

  // initial gx prefetch (s = 0)
  ushort4 gxv[3];
#pragma unroll
  for (int p = 0; p < 3; ++p) gxv[p] = *(const ushort4*)(gptr + goff[p]);

#pragma unroll 2
  for (int s = 0; s < TT; ++s) {
    const int pb = s & 1;

    // accumulator init straight from gx (D layout matches ushort4 lanes)
    f32x4 acc[3];
#pragma unroll
    for (int p = 0; p < 3; ++p) {
      acc[p][0] = bf2f(gxv[p].x); acc[p][1] = bf2f(gxv[p].y);
      acc[p][2] = bf2f(gxv[p].z); acc[p][3] = bf2f(gxv[p].w);
    }
    // prefetch next step's gx
    gptr += gstep;
#pragma unroll
    for (int p = 0; p < 3; ++p) gxv[p] = *(const ushort4*)(gptr + goff[p]);

    // gates += h @ W_hh^T over the FULL h (both halves resident in hk)
#pragma unroll
    for (int kt = 0; kt < 8; ++kt) {
      bhalf8 a = __builtin_bit_cast(bhalf8, hk[pb][kt][lane]);
      acc[0] = __builtin_amdgcn_mfma_f32_16x16x32_bf16(a, wreg[0][kt], acc[0], 0, 0, 0);
      acc[1] = __builtin_amdgcn_mfma_f32_16x16x32_bf16(a, wreg[1][kt], acc[1], 0, 0, 0);
      acc[2] = __builtin_amdgcn_mfma_f32_16x16x32_bf16(
          a, __builtin_bit_cast(bhalf8, wlds[w][kt][lane]), acc[2], 0, 0, 0);
    }

    // epilogue: coupled-gate update (i=acc0, c=acc1, o=acc2; prescaled)
    float ei[4], ec[4], eo[4];
#pragma unroll
    for (int r = 0; r < 4; ++r) {
      ei[r] = __builtin_amdgcn_exp2f(clamp24(-acc[0][r]));
      ec[r] = __builtin_amdgcn_exp2f(clamp24( acc[1][r]));
      eo[r] = __builtin_amdgcn_exp2f(clamp24(-acc[2][r]));
    }
    float ig[4], tc[4], og[4];
    inv4(1.f + ei[0], 1.f + ei[1], 1.f + ei[2], 1.f + ei[3],
         ig[0], ig[1], ig[2], ig[3]);
    inv4(1.f + ec[0], 1.f + ec[1], 1.f + ec[2], 1.f + ec[3],
         tc[0], tc[1], tc[2], tc[3]);
    inv4(1.f + eo[0], 1.f + eo[1], 1.f + eo[2], 1.f + eo[3],
         og[0], og[1], og[2], og[3]);
    float cvv[4], et[4];
#pragma unroll
    for (int r = 0; r < 4; ++r) {
      float cg = __builtin_fmaf(-2.f, tc[r], 1.f);       // tanh(c-gate)
      float cp = cstate[r];
      float cv = __builtin_fmaf(ig[r], cg - cp, cp);     // (1-i)c + i*g, |cv|<=1
      cstate[r] = cv;
      cvv[r] = cv;
      et[r] = __builtin_amdgcn_exp2f(cv * LOG2E2);
    }
    float it4[4];
    inv4(1.f + et[0], 1.f + et[1], 1.f + et[2], 1.f + et[3],
         it4[0], it4[1], it4[2], it4[3]);
    float hv[4];
#pragma unroll
    for (int r = 0; r < 4; ++r)
      hv[r] = og[r] * __builtin_fmaf(-2.f, it4[r], 1.f); // o * tanh(c)

    // own-half h -> local fragment LDS
    unsigned short* hbj = (unsigned short*)hk[pb ^ 1][ktb_own] + chunk_base;
    unsigned u01 = cvt_pk_bf16(hv[0], hv[1]);
    unsigned u23 = cvt_pk_bf16(hv[2], hv[3]);
    hbj[0]  = (unsigned short)u01;
    hbj[8]  = (unsigned short)(u01 >> 16);
    hbj[16] = (unsigned short)u23;
    hbj[24] = (unsigned short)(u23 >> 16);

#pragma unroll
    for (int r = 0; r < 4; ++r) orow[(size_t)r * 512] = hv[r];
    orow += ostep;

    if (s < TT - 1) {
      // publish own half for the partner (lane-linear packed, 8B/thread)
      uint2 px; px.x = u01; px.y = u23;
      hxch[(s + 1) & 1][bid][tid] = px;
      __syncthreads();                       // all waves' stores drained (vmcnt 0)
      if (tid == 0) {
        __builtin_amdgcn_fence(__ATOMIC_RELEASE, "agent");
        __hip_atomic_store(&rec_flags[bid], (unsigned)(s + 1),
                           __ATOMIC_RELAXED, __HIP_MEMORY_SCOPE_AGENT);
      }
      // acquire partner's half of h_{s+1}
      while (__hip_atomic_load(&rec_flags[pbid], __ATOMIC_RELAXED,
                               __HIP_MEMORY_SCOPE_AGENT) < (unsigned)(s + 1)) {
        __builtin_amdgcn_s_sleep(1);
      }
      __builtin_amdgcn_fence(__ATOMIC_ACQUIRE, "agent");
      uint2 qx = hxch[(s + 1) & 1][pbid][tid];
      unsigned short* pbj = (unsigned short*)hk[pb ^ 1][ktb_par] + chunk_base;
      pbj[0]  = (unsigned short)qx.x;
      pbj[8]  = (unsigned short)(qx.x >> 16);
      pbj[16] = (unsigned short)qx.y;
      pbj[24] = (unsigned short)(qx.y >> 16);
      __syncthreads();                       // h_{s+1} fully assembled
    } else {
#pragma unroll
      for (int r = 0; r < 4; ++r) {
        int brow = b0 + quad * 4 + r;
        int col  = half * 128 + 16 * w + l15;
        hn[(size_t)brow * 512 + dir * 256 + col] = hv[r];
        cn[(size_t)brow * 512 + dir * 256 + col] = cvv[r];
      }
    }
  }
}

// ---------------------------------------------------------------------------
extern "C" void kernel_launch(void* const* d_in, const int* in_sizes, int n_in,
                              void* d_out, int out_size, void* d_ws, size_t ws_size,
                              hipStream_t stream) {
  const float* X     = (const float*)d_in[0];
  const float* wih_f = (const float*)d_in[1];
  const float* whh_f = (const float*)d_in[2];
  const float* bih_f = (const float*)d_in[3];
  const float* bhh_f = (const float*)d_in[4];
  const float* wih_b = (const float*)d_in[5];
  const float* whh_b = (const float*)d_in[6];
  const float* bih_b = (const float*)d_in[7];
  const float* bhh_b = (const float*)d_in[8];
  float* out = (float*)d_out;
  unsigned short* gxbuf = (unsigned short*)d_ws;   // 2*1024*768*64*2B = 192 MiB

  gx_kernel<<<768, 1024, 0, stream>>>(X, wih_f, bih_f, bhh_f, wih_b, bih_b, bhh_b, gxbuf);
  rec_kernel<<<16, 512, 0, stream>>>(whh_f, whh_b, gxbuf, out);
}

// Round 6
// 1879.242 us; speedup vs baseline: 2.0605x; 2.0605x over previous
//
#include <hip/hip_runtime.h>
#include <cstdint>
#include <cstddef>

// Problem constants
#define TT 1024
#define NB 64
#define HD 256
#define NG 768   // 3*H

typedef short bhalf8 __attribute__((ext_vector_type(8)));   // 8 bf16 (4 VGPRs)
typedef float f32x4  __attribute__((ext_vector_type(4)));   // MFMA accumulator

#define LOG2E  1.4426950408889634f
#define LOG2E2 2.8853900817779268f   // 2*log2e (c-gate rows: folds the 2x in tanh)

__device__ __forceinline__ float bf2f(unsigned short s) {
  return __uint_as_float(((unsigned)s) << 16);
}
__device__ __forceinline__ unsigned cvt_pk_bf16(float lo, float hi) {
  unsigned r;
  asm("v_cvt_pk_bf16_f32 %0, %1, %2" : "=v"(r) : "v"(lo), "v"(hi));
  return r;
}
// single-instruction clamp to +-24 (v_med3_f32)
__device__ __forceinline__ float clamp24(float x) {
  return __builtin_amdgcn_fmed3f(x, -24.0f, 24.0f);
}
// Barrier that waits ONLY on LDS ops (lgkmcnt), not vmcnt: avoids draining
// in-flight global stores/prefetches every step (the m97 barrier-drain stall;
// __syncthreads emits s_waitcnt vmcnt(0) lgkmcnt(0) + s_barrier).
__device__ __forceinline__ void lds_barrier() {
  asm volatile("s_waitcnt lgkmcnt(0)\n\ts_barrier" ::: "memory");
}
// Batched reciprocal: 4 divides for the price of 1 v_rcp + 9 v_mul.
// All inputs in [1, 1+2^24] -> product <= 2^97, no overflow.
__device__ __forceinline__ void inv4(float d0, float d1, float d2, float d3,
                                     float& i0, float& i1, float& i2, float& i3) {
  float p2 = d0 * d1;
  float p3 = p2 * d2;
  float p4 = p3 * d3;
  float r  = __builtin_amdgcn_rcpf(p4);
  i3 = r * p3;
  float r3 = r * d3;      // 1/p3
  i2 = r3 * p2;
  float r2 = r3 * d2;     // 1/p2
  i1 = r2 * d0;
  i0 = r2 * d1;
}

// gx layout: [dir][slice(4)][t][g][b16]  (slice = batch/16, b16 = batch%16)
// gx values are PRESCALED: i/o-gate rows by log2e, c-gate rows by 2*log2e.
#define GX_SLICE ((size_t)TT * NG * 16)

// ---------------------------------------------------------------------------
// Kernel 1: gx = (X @ W_ih^T + biases) * gate_scale, bf16, swizzled layout.
// 1D grid 768 with XCD-aware swizzle: the 12 gate-tile blocks that share one
// X t-tile all land on the same XCD -> X re-reads served from that XCD's L2;
// W_ih becomes L2-resident per XCD.
// ---------------------------------------------------------------------------
__attribute__((amdgpu_flat_work_group_size(1024, 1024)))
__attribute__((amdgpu_waves_per_eu(4, 4)))
__global__ void gx_kernel(const float* __restrict__ X,
                          const float* __restrict__ wih_f, const float* __restrict__ bih_f,
                          const float* __restrict__ bhh_f,
                          const float* __restrict__ wih_b, const float* __restrict__ bih_b,
                          const float* __restrict__ bhh_b,
                          unsigned short* __restrict__ gx) {
  const int tid = threadIdx.x;
  // XCD swizzle: xcd = bid&7; within XCD: 12 gate-tiles x 8 t-tiles
  const int bid  = blockIdx.x;
  const int xcd  = bid & 7;
  const int i    = bid >> 3;           // 0..95
  const int n0   = (i % 12) * 64;      // gate-col tile (single gate type)
  const int t0   = (xcd + 8 * (i / 12)) * 16;

  __shared__ unsigned short Al[2][64][264];   // X tile [buf][b][k], double-buffered

  const int lane = tid & 63, w = tid >> 6, quad = lane >> 4, l15 = lane & 15;
  const int sl = w & 3;          // batch slice
  const int jt = w >> 2;         // gate subtile
  const int g  = n0 + jt * 16 + l15;   // this lane's gate row
  const float wsc = (n0 >= 256 && n0 < 512) ? LOG2E2 : LOG2E;

  // ---- W_ih fragments for both dirs, in registers (8 bhalf8 per dir) ----
  bhalf8 wreg[2][8];
#pragma unroll
  for (int dir = 0; dir < 2; ++dir) {
    const float* wih = dir ? wih_b : wih_f;
#pragma unroll
    for (int kt = 0; kt < 8; ++kt) {
      const float* wp = wih + (size_t)g * HD + kt * 32 + quad * 8;
      float4 v0 = *(const float4*)wp;
      float4 v1 = *(const float4*)(wp + 4);
      union { bhalf8 v; uint4 u; } pk;
      pk.u.x = cvt_pk_bf16(v0.x * wsc, v0.y * wsc);
      pk.u.y = cvt_pk_bf16(v0.z * wsc, v0.w * wsc);
      pk.u.z = cvt_pk_bf16(v1.x * wsc, v1.y * wsc);
      pk.u.w = cvt_pk_bf16(v1.z * wsc, v1.w * wsc);
      wreg[dir][kt] = pk.v;
    }
  }
  const float bias_f = (bih_f[g] + bhh_f[g]) * wsc;
  const float bias_b = (bih_b[g] + bhh_b[g]) * wsc;

#define STAGE_X(ttv, buf)                                                     \
  {                                                                           \
    const int t = t0 + (ttv);                                                 \
    _Pragma("unroll")                                                         \
    for (int ii = 0; ii < 4; ++ii) {                                          \
      int f4  = tid + ii * 1024;                                              \
      int row = f4 >> 6;                                                      \
      int kk  = (f4 & 63) * 4;                                                \
      float4 xv = *(const float4*)(X + ((size_t)row * TT + t) * HD + kk);     \
      uint2 p;                                                                \
      p.x = cvt_pk_bf16(xv.x, xv.y);                                          \
      p.y = cvt_pk_bf16(xv.z, xv.w);                                          \
      *(uint2*)&Al[buf][row][kk] = p;                                         \
    }                                                                         \
  }

  STAGE_X(0, 0);

  for (int tt = 0; tt < 16; ++tt) {
    const int buf = tt & 1;
    lds_barrier();                // Al[buf] staged & visible; prior reads done
    if (tt < 15) STAGE_X(tt + 1, buf ^ 1);

    f32x4 acc0 = {0.f, 0.f, 0.f, 0.f};   // dir 0
    f32x4 acc1 = {0.f, 0.f, 0.f, 0.f};   // dir 1
#pragma unroll
    for (int kt = 0; kt < 8; ++kt) {
      bhalf8 a = *(const bhalf8*)&Al[buf][16 * sl + l15][kt * 32 + quad * 8];
      acc0 = __builtin_amdgcn_mfma_f32_16x16x32_bf16(a, wreg[0][kt], acc0, 0, 0, 0);
      acc1 = __builtin_amdgcn_mfma_f32_16x16x32_bf16(a, wreg[1][kt], acc1, 0, 0, 0);
    }

    const int t = t0 + tt;
    {
      unsigned short* gs = gx + sl * GX_SLICE + (size_t)t * NG * 16 + g * 16 + quad * 4;
      uint2 p;
      p.x = cvt_pk_bf16(acc0[0] + bias_f, acc0[1] + bias_f);
      p.y = cvt_pk_bf16(acc0[2] + bias_f, acc0[3] + bias_f);
      *(uint2*)gs = p;
      unsigned short* gs1 = gs + 4 * GX_SLICE;
      uint2 q;
      q.x = cvt_pk_bf16(acc1[0] + bias_b, acc1[1] + bias_b);
      q.y = cvt_pk_bf16(acc1[2] + bias_b, acc1[3] + bias_b);
      *(uint2*)gs1 = q;
    }
  }
#undef STAGE_X
}

// ---------------------------------------------------------------------------
// Kernel 2: recurrence (reverted to the proven 8-block structure; the 16-block
// H-split with per-step global h-exchange cost +4900 cy/step and is dead).
// 8 blocks = 2 dirs x 4 batch-slices of 16; 1024 threads = 16 waves ->
// 4 waves/SIMD covers trans/LDS/MFMA latency inside the barrier-locked step.
// 128 regs/wave: W_hh 2 tiles in regs + 1 in LDS (128 KB). Wave owns one
// 16-col gate triple (i,c,o). Per-step barrier is lgkmcnt-only: the 4 output
// stores + 3 gx prefetches stay in flight across it (no vmcnt(0) drain).
// ---------------------------------------------------------------------------
__attribute__((amdgpu_flat_work_group_size(1024, 1024)))
__attribute__((amdgpu_waves_per_eu(4, 4)))
__global__ void rec_kernel(const float* __restrict__ whh_f,
                           const float* __restrict__ whh_b,
                           const unsigned short* __restrict__ gx,
                           float* __restrict__ out) {
  const int tid  = threadIdx.x;
  const int lane = tid & 63, w = tid >> 6, quad = lane >> 4, l15 = lane & 15;
  const int blk = blockIdx.x;          // 0..7
  const int dir = blk >> 2;
  const int b0  = (blk & 3) * 16;
  const float* whh = dir ? whh_b : whh_f;
  const unsigned short* gxd = gx + (size_t)dir * 4 * GX_SLICE + (size_t)(blk & 3) * GX_SLICE;
  float* hn = out + (size_t)TT * NB * 512;
  float* cn = hn + (size_t)NB * 512;

  __shared__ uint4 wlds[16][8][64];  // 128 KB: [wave][kt][lane] W-frags, tile p=2
  __shared__ uint4 hk[2][8][64];     // 16 KB: [buf][kt][chunk] h fragment layout
  // chunk = quadA*16 + m : holds A[m][kt*32+quadA*8 .. +8) as 8 bf16

  // ---- load W_hh fragments (one-time), prescaled by gate type ----
  // wave w owns gate cols [16w,16w+16) of each group p: n = p*256 + 16w + l15
  bhalf8 wreg[2][8];
#pragma unroll
  for (int p = 0; p < 3; ++p) {
    int n = p * 256 + 16 * w + l15;
    const float wscp = (p == 1) ? LOG2E2 : LOG2E;
#pragma unroll
    for (int kt = 0; kt < 8; ++kt) {
      const float* wp = whh + (size_t)n * HD + kt * 32 + quad * 8;
      float4 v0 = *(const float4*)wp;
      float4 v1 = *(const float4*)(wp + 4);
      union { bhalf8 v; uint4 u; } pk;
      pk.u.x = cvt_pk_bf16(v0.x * wscp, v0.y * wscp);
      pk.u.y = cvt_pk_bf16(v0.z * wscp, v0.w * wscp);
      pk.u.z = cvt_pk_bf16(v1.x * wscp, v1.y * wscp);
      pk.u.w = cvt_pk_bf16(v1.z * wscp, v1.w * wscp);
      if (p < 2) wreg[p][kt] = pk.v;
      else       wlds[w][kt][lane] = pk.u;
    }
  }

  // zero h_0 buffer (only hk[0] read at s=0)
  if (tid < 512) {
    uint4 z; z.x = z.y = z.z = z.w = 0;
    ((uint4*)hk[0])[tid] = z;
  }

  float cstate[4];
#pragma unroll
  for (int r = 0; r < 4; ++r) cstate[r] = 0.0f;

  int goff[3];
#pragma unroll
  for (int p = 0; p < 3; ++p) {
    int g = p * 256 + 16 * w + l15;
    goff[p] = g * 16 + quad * 4;     // within-slice offset (b16 = quad*4..+3)
  }

  __syncthreads();

  // uniform gx walk pointer (SGPR side): t=0 forward, t=TT-1 backward.
  // Final (unused) prefetch one step past the range stays inside the 192 MiB
  // workspace for both directions.
  const unsigned short* gptr = gxd + (size_t)(dir ? (TT - 1) : 0) * NG * 16;
  const ptrdiff_t gstep = dir ? -(ptrdiff_t)((size_t)NG * 16) : (ptrdiff_t)((size_t)NG * 16);

  // output row pointer walk (no per-step 64-bit mul); h-col = 16w + l15
  float* orow = out + ((size_t)(dir ? (TT - 1) : 0) * NB + b0 + quad * 4) * 512
                + dir * 256 + 16 * w + l15;
  const ptrdiff_t ostep = dir ? -(ptrdiff_t)(NB * 512) : (ptrdiff_t)(NB * 512);

  // initial gx prefetch (s = 0)
  ushort4 gxv[3];
#pragma unroll
  for (int p = 0; p < 3; ++p) gxv[p] = *(const ushort4*)(gptr + goff[p]);

#pragma unroll 2
  for (int s = 0; s < TT; ++s) {
    const int pb = s & 1;

    // accumulator init straight from gx (D layout matches ushort4 lanes)
    f32x4 acc[3];
#pragma unroll
    for (int p = 0; p < 3; ++p) {
      acc[p][0] = bf2f(gxv[p].x); acc[p][1] = bf2f(gxv[p].y);
      acc[p][2] = bf2f(gxv[p].z); acc[p][3] = bf2f(gxv[p].w);
    }
    // prefetch next step's gx (one-past-range on last step; values unused)
    gptr += gstep;
#pragma unroll
    for (int p = 0; p < 3; ++p) gxv[p] = *(const ushort4*)(gptr + goff[p]);

    // gates += h @ W_hh^T ; A-frag read is lane-linear (conflict-free)
#pragma unroll
    for (int kt = 0; kt < 8; ++kt) {
      bhalf8 a = __builtin_bit_cast(bhalf8, hk[pb][kt][lane]);
      acc[0] = __builtin_amdgcn_mfma_f32_16x16x32_bf16(a, wreg[0][kt], acc[0], 0, 0, 0);
      acc[1] = __builtin_amdgcn_mfma_f32_16x16x32_bf16(a, wreg[1][kt], acc[1], 0, 0, 0);
      acc[2] = __builtin_amdgcn_mfma_f32_16x16x32_bf16(
          a, __builtin_bit_cast(bhalf8, wlds[w][kt][lane]), acc[2], 0, 0, 0);
    }

    // epilogue: coupled-gate update. acc[0]=i (log2e), acc[1]=c (2log2e),
    // acc[2]=o (log2e). sigma(x)=rcp(1+exp2(-a)), tanh(x)=1-2*rcp(1+exp2(a)).
    unsigned short* hnext = (unsigned short*)hk[pb ^ 1][w >> 1];
    float ei[4], ec[4], eo[4];
#pragma unroll
    for (int r = 0; r < 4; ++r) {
      ei[r] = __builtin_amdgcn_exp2f(clamp24(-acc[0][r]));
      ec[r] = __builtin_amdgcn_exp2f(clamp24( acc[1][r]));
      eo[r] = __builtin_amdgcn_exp2f(clamp24(-acc[2][r]));
    }
    float ig[4], tc[4], og[4];
    inv4(1.f + ei[0], 1.f + ei[1], 1.f + ei[2], 1.f + ei[3],
         ig[0], ig[1], ig[2], ig[3]);
    inv4(1.f + ec[0], 1.f + ec[1], 1.f + ec[2], 1.f + ec[3],
         tc[0], tc[1], tc[2], tc[3]);
    inv4(1.f + eo[0], 1.f + eo[1], 1.f + eo[2], 1.f + eo[3],
         og[0], og[1], og[2], og[3]);
    float cvv[4], et[4];
#pragma unroll
    for (int r = 0; r < 4; ++r) {
      float cg = __builtin_fmaf(-2.f, tc[r], 1.f);       // tanh(c-gate)
      float cp = cstate[r];
      float cv = __builtin_fmaf(ig[r], cg - cp, cp);     // (1-i)c + i*g, |cv|<=1
      cstate[r] = cv;
      cvv[r] = cv;
      et[r] = __builtin_amdgcn_exp2f(cv * LOG2E2);       // no clamp needed, |cv|<=1
    }
    float it4[4];
    inv4(1.f + et[0], 1.f + et[1], 1.f + et[2], 1.f + et[3],
         it4[0], it4[1], it4[2], it4[3]);
    float hv[4];
#pragma unroll
    for (int r = 0; r < 4; ++r)
      hv[r] = og[r] * __builtin_fmaf(-2.f, it4[r], 1.f); // o * tanh(c)

    // h -> fragment layout: col = 16w + l15 -> kt-block = w>>1,
    // quadA = (w&1)*2 + (l15>>3), chunk = quadA*16 + quad*4 + r, slot = l15&7
    unsigned short* hbj = hnext
        + (size_t)(((((w & 1) * 2 + (l15 >> 3)) * 16) + quad * 4) * 8) + (l15 & 7);
    unsigned u01 = cvt_pk_bf16(hv[0], hv[1]);
    unsigned u23 = cvt_pk_bf16(hv[2], hv[3]);
    hbj[0]  = (unsigned short)u01;
    hbj[8]  = (unsigned short)(u01 >> 16);
    hbj[16] = (unsigned short)u23;
    hbj[24] = (unsigned short)(u23 >> 16);

#pragma unroll
    for (int r = 0; r < 4; ++r) {
      orow[(size_t)r * 512 + 0] = hv[r];
      if (s == TT - 1) {
        int brow = b0 + quad * 4 + r;
        int col  = 16 * w + l15;
        hn[(size_t)brow * 512 + dir * 256 + col] = hv[r];
        cn[(size_t)brow * 512 + dir * 256 + col] = cvv[r];
      }
    }
    orow += ostep;
    lds_barrier();     // h_{s+1} published (LDS only; stores stay in flight)
  }
}

// ---------------------------------------------------------------------------
extern "C" void kernel_launch(void* const* d_in, const int* in_sizes, int n_in,
                              void* d_out, int out_size, void* d_ws, size_t ws_size,
                              hipStream_t stream) {
  const float* X     = (const float*)d_in[0];
  const float* wih_f = (const float*)d_in[1];
  const float* whh_f = (const float*)d_in[2];
  const float* bih_f = (const float*)d_in[3];
  const float* bhh_f = (const float*)d_in[4];
  const float* wih_b = (const float*)d_in[5];
  const float* whh_b = (const float*)d_in[6];
  const float* bih_b = (const float*)d_in[7];
  const float* bhh_b = (const float*)d_in[8];
  float* out = (float*)d_out;
  unsigned short* gxbuf = (unsigned short*)d_ws;   // 2*1024*768*64*2B = 192 MiB

  gx_kernel<<<768, 1024, 0, stream>>>(X, wih_f, bih_f, bhh_f, wih_b, bih_b, bhh_b, gxbuf);
  rec_kernel<<<8, 1024, 0, stream>>>(whh_f, whh_b, gxbuf, out);
}